// Round 7
// baseline (961.977 us; speedup 1.0000x reference)
//
#include <hip/hip_runtime.h>
#include <math.h>

typedef short bf16x8 __attribute__((ext_vector_type(8)));
typedef float f32x4 __attribute__((ext_vector_type(4)));

__device__ __forceinline__ unsigned short f2bf(float x) {
  union { float f; unsigned u; } v; v.f = x;
  unsigned r = v.u + 0x7FFFu + ((v.u >> 16) & 1u);
  return (unsigned short)(r >> 16);
}
__device__ __forceinline__ float bf2f(unsigned short h) {
  union { unsigned u; float f; } v; v.u = ((unsigned)h) << 16; return v.f;
}

// ---------------- workspace layout (bytes) ----------------
#define WS_WAUG  0u         // [768][288] bf16 (Whh^T | Wih^T | bias | 0)
#define WS_W1T   442368u    // [512][256] bf16
#define WS_HAUGA 704512u    // [2048][288] bf16  (h bf16 | feats | 1 | 0)
#define WS_HAUGB 1884160u   // [2048][288] bf16
#define WS_HF32  3063808u   // [2048][256] f32 (h state; ACTS overlays after GRU)
#define WS_ACTS  3063808u   // [2048][512] bf16 (overlays HF32, used post-GRU)
#define WS_LAM   5160960u   // [2048][22] f32
#define WS_KKT   5341184u   // 4 x [11][16] f32
#define WS_GX    5344000u   // [11][16] f32
#define WS_GY    5344704u   // [11][16] f32
#define WS_MX    5345408u   // [11][16] f32
#define WS_MY    5346112u   // [11][16] f32
#define WS_SUMS  5346816u   // sumP[11], sumPDOT[11]
#define WS_BAR   5346944u   // grid barrier counter (u32)

// ---------------- grid barrier (monotonic counter, agent scope) ----------------
__device__ __forceinline__ void gridbar(unsigned int* ctr, unsigned int target) {
  __threadfence();            // release: order/flush this thread's prior stores
  __syncthreads();
  if (threadIdx.x == 0) {
    __hip_atomic_fetch_add(ctr, 1u, __ATOMIC_ACQ_REL, __HIP_MEMORY_SCOPE_AGENT);
    while (__hip_atomic_load(ctr, __ATOMIC_ACQUIRE, __HIP_MEMORY_SCOPE_AGENT) < target)
      __builtin_amdgcn_s_sleep(1);
  }
  __syncthreads();
  __threadfence();            // acquire side: invalidate stale cached lines
}

// ---------------- prep: KKT inverses + M/G matrices (blocks 0-3) + packing ----------------
__global__ __launch_bounds__(256) void prep(
    const float* __restrict__ Whh, const float* __restrict__ Wih,
    const float* __restrict__ gb, const float* __restrict__ W1,
    const float* __restrict__ h0,
    const float* __restrict__ obs, const float* __restrict__ dimx,
    const float* __restrict__ dimy, const float* __restrict__ psi,
    unsigned short* __restrict__ Waug, unsigned short* __restrict__ W1T,
    unsigned short* __restrict__ HaugA, unsigned short* __restrict__ HaugB,
    float* __restrict__ kkt_out, float* __restrict__ Gx_out,
    float* __restrict__ Gy_out, float* __restrict__ Mx_out,
    float* __restrict__ My_out, float* __restrict__ sums_out,
    unsigned int* __restrict__ bar)
{
  __shared__ double S[21];
  __shared__ double Spow[21][104];
  __shared__ double aug[15][32];
  __shared__ double fbuf[15];
  __shared__ double Md[11][11];
  if (blockIdx.x == 0 && threadIdx.x == 0) bar[0] = 0u;
  if (blockIdx.x < 4) {
    const int mat = blockIdx.x;
    const int n = (mat == 0 || mat == 2) ? 15 : 14;
    const int twoN = 2 * n;
    if (threadIdx.x < 100) {
      double t = threadIdx.x * (1.0 / 99.0);
      double p = 1.0;
      for (int m = 0; m < 21; ++m) { Spow[m][threadIdx.x] = p; p *= t; }
    }
    __syncthreads();
    if (threadIdx.x < 21) {
      double s = 0.0;
      for (int k = 0; k < 100; ++k) s += Spow[threadIdx.x][k];
      S[threadIdx.x] = s;
    }
    __syncthreads();
    for (int idx = threadIdx.x; idx < n * twoN; idx += 256) {
      int r = idx / twoN, c = idx % twoN;
      double v;
      if (c >= n) v = (c - n == r) ? 1.0 : 0.0;
      else if (r < 11 && c < 11) {
        double ptp = S[r + c];
        double pdp = (r >= 1 && c >= 1) ? ((double)(r * c) / 100.0) * S[r + c - 2] : 0.0;
        double pddp = (r >= 2 && c >= 2) ? ((double)(r*(r-1)) * (double)(c*(c-1)) / 10000.0) * S[r + c - 4] : 0.0;
        double dg = (r == c) ? 1.0 : 0.0;
        if (mat == 0)      v = 21.0*dg + 30.0*ptp + pdp + pddp;
        else if (mat == 1) v = 21.0*dg + 32.0*ptp + pdp + pddp;
        else if (mat == 2) v = 20.0*dg + 2.0*pdp;
        else               v = 20.0*dg + 2.0*pdp + ptp;
      } else if (r >= 11 && c >= 11) v = 0.0;
      else {
        int ar = (r >= 11) ? (r - 11) : (c - 11);
        int ac = (r >= 11) ? c : r;
        v = (ar == 0) ? ((ac == 0) ? 1.0 : 0.0)
          : (ar == 1) ? ((ac == 1) ? 0.1 : 0.0)
          : (ar == 2) ? ((ac == 2) ? 0.02 : 0.0)
          : 1.0;
      }
      aug[r][c] = v;
    }
    __syncthreads();
    for (int p = 0; p < n; ++p) {
      double pv = aug[p][p];
      __syncthreads();
      double inv = 1.0 / pv;
      for (int c = threadIdx.x; c < twoN; c += 256) aug[p][c] *= inv;
      __syncthreads();
      if (threadIdx.x < n) fbuf[threadIdx.x] = aug[threadIdx.x][p];
      __syncthreads();
      for (int idx = threadIdx.x; idx < n * twoN; idx += 256) {
        int r = idx / twoN, c = idx % twoN;
        if (r != p) aug[r][c] -= fbuf[r] * aug[p][c];
      }
      __syncthreads();
    }
    for (int idx = threadIdx.x; idx < 11 * n; idx += 256) {
      int r = idx / n, c = idx % n;
      kkt_out[mat * 176 + r * 16 + c] = (float)aug[r][n + c];
    }
    if (mat < 2) {
      if (threadIdx.x < 121) {
        int j = threadIdx.x / 11, i = threadIdx.x % 11;
        double m = 30.0 * S[j + i];
        if (j >= 1 && i >= 1) m += ((double)(j * i) / 100.0) * S[j + i - 2];
        if (j >= 2 && i >= 2) m += ((double)(j*(j-1)) * (double)(i*(i-1)) / 10000.0) * S[j + i - 4];
        if (mat == 1) m += 2.0 * S[j + i];
        Md[j][i] = m;
      }
      __syncthreads();
      if (threadIdx.x < 121) {
        int j = threadIdx.x / 11, i = threadIdx.x % 11;
        double g = (j == i) ? 1.0 : 0.0;
        for (int k = 0; k < 11; ++k) g -= Md[j][k] * aug[k][n + i];
        if (mat == 0) { Gx_out[j * 16 + i] = (float)g; Mx_out[j * 16 + i] = (float)Md[j][i]; }
        else          { Gy_out[j * 16 + i] = (float)g; My_out[j * 16 + i] = (float)Md[j][i]; }
      }
    }
    if (mat == 0 && threadIdx.x < 11) {
      int j = threadIdx.x;
      sums_out[j] = (float)S[j];
      sums_out[11 + j] = (j >= 1) ? (float)((double)j / 10.0 * S[j - 1]) : 0.f;
    }
    return;
  }
  int idx = (blockIdx.x - 4) * 256 + threadIdx.x;
  if (idx < 221184) {           // Waug[col][k], k in [0,288)
    int col = idx / 288, k = idx - col * 288;
    float v;
    if (k < 256)       v = Whh[k * 768 + col];
    else if (k < 261)  v = Wih[(k - 256) * 768 + col];
    else if (k == 261) v = gb[col];
    else               v = 0.f;
    Waug[idx] = f2bf(v);
  } else if (idx < 352256) {    // W1T[col][k]
    int j = idx - 221184;
    int col = j >> 8, k = j & 255;
    W1T[j] = f2bf(W1[k * 512 + col]);
  } else if (idx < 942080) {    // HaugA full init
    int j = idx - 352256;
    int row = j / 288, k = j - row * 288;
    float v;
    if (k < 256)       v = h0[k];
    else if (k == 256) v = obs[row * 20 + 0];
    else if (k == 257) v = obs[row * 20 + 10];
    else if (k == 258) v = dimx[row * 10 + 0];
    else if (k == 259) v = dimy[row * 10 + 0];
    else if (k == 260) v = psi[row * 10 + 0];
    else if (k == 261) v = 1.0f;
    else               v = 0.f;
    HaugA[row * 288 + k] = f2bf(v);
  } else if (idx < 995328) {    // HaugB: constant tail zeros (k=262..287)
    int j = idx - 942080;
    int row = j / 26, k = 262 + (j - row * 26);
    HaugB[row * 288 + k] = 0;
  }
}

// ---------------- persistent NN: 10 GRU steps + MLP1 + MLP2 (256 blocks x 256) ----------------
#define MFMA __builtin_amdgcn_mfma_f32_16x16x32_bf16
__global__ __launch_bounds__(256) void nn_all(
    const unsigned short* __restrict__ Waug,
    unsigned short* __restrict__ HaugA, unsigned short* __restrict__ HaugB,
    float* __restrict__ Hf32, const float* __restrict__ h0,
    const float* __restrict__ obs, const float* __restrict__ dimx,
    const float* __restrict__ dimy, const float* __restrict__ psi,
    const unsigned short* __restrict__ W1T, const float* __restrict__ b1,
    const float* __restrict__ W2, const float* __restrict__ b2,
    unsigned short* __restrict__ acts, float* __restrict__ lam,
    unsigned int* __restrict__ bar)
{
  __shared__ __align__(16) unsigned char smem[53376];
  const int tid = threadIdx.x;
  const int bid = blockIdx.x;
  const int lane = tid & 63, w = tid >> 6;
  const int l15 = lane & 15, g4 = lane >> 4;

  // ======== GRU: block = 32 rows x 64 cols; wave w owns 16 cols, both row halves ========
  {
    const int m0 = (bid >> 2) * 32;
    const int c0 = (bid & 3) * 64;
    const int cw = c0 + w * 16 + l15;
    const float h0c = h0[cw];
    for (int s = 0; s < 10; ++s) {
      const unsigned short* HaugC = (s & 1) ? HaugB : HaugA;
      unsigned short* HaugN = (s & 1) ? HaugA : HaugB;
      const unsigned short* Arow0 = HaugC + (size_t)(m0 + l15) * 288 + g4 * 8;
      const unsigned short* Arow1 = HaugC + (size_t)(m0 + 16 + l15) * 288 + g4 * 8;
      const unsigned short* Bc = Waug + (size_t)cw * 288 + g4 * 8;
      f32x4 az0 = {0.f,0.f,0.f,0.f}, az1 = {0.f,0.f,0.f,0.f};
      f32x4 ar0 = {0.f,0.f,0.f,0.f}, ar1 = {0.f,0.f,0.f,0.f};
      f32x4 nh0 = {0.f,0.f,0.f,0.f}, nh1 = {0.f,0.f,0.f,0.f};
      f32x4 nx0 = {0.f,0.f,0.f,0.f}, nx1 = {0.f,0.f,0.f,0.f};
      #pragma unroll
      for (int kc = 0; kc < 9; ++kc) {
        bf16x8 a0 = *(const bf16x8*)(Arow0 + kc * 32);
        bf16x8 a1 = *(const bf16x8*)(Arow1 + kc * 32);
        bf16x8 bz = *(const bf16x8*)(Bc + kc * 32);
        bf16x8 br = *(const bf16x8*)(Bc + 256 * 288 + kc * 32);
        bf16x8 bn = *(const bf16x8*)(Bc + 512 * 288 + kc * 32);
        az0 = MFMA(a0, bz, az0, 0, 0, 0);
        az1 = MFMA(a1, bz, az1, 0, 0, 0);
        ar0 = MFMA(a0, br, ar0, 0, 0, 0);
        ar1 = MFMA(a1, br, ar1, 0, 0, 0);
        if (kc < 8) { nh0 = MFMA(a0, bn, nh0, 0, 0, 0); nh1 = MFMA(a1, bn, nh1, 0, 0, 0); }
        else        { nx0 = MFMA(a0, bn, nx0, 0, 0, 0); nx1 = MFMA(a1, bn, nx1, 0, 0, 0); }
      }
      #pragma unroll
      for (int mi = 0; mi < 2; ++mi) {
        f32x4 az = mi ? az1 : az0, arr = mi ? ar1 : ar0;
        f32x4 nh = mi ? nh1 : nh0, nx = mi ? nx1 : nx0;
        #pragma unroll
        for (int rg = 0; rg < 4; ++rg) {
          int row = m0 + mi * 16 + g4 * 4 + rg;
          float hold = (s == 0) ? h0c : Hf32[(size_t)row * 256 + cw];
          float z = 1.f / (1.f + __expf(-az[rg]));
          float rr = 1.f / (1.f + __expf(-arr[rg]));
          float nn = tanhf(nx[rg] + rr * nh[rg]);
          float hnew = (1.f - z) * nn + z * hold;
          Hf32[(size_t)row * 256 + cw] = hnew;
          HaugN[(size_t)row * 288 + cw] = f2bf(hnew);
        }
      }
      if ((bid & 3) == 0 && s < 9 && tid < 192) {
        int row = m0 + tid / 6, e = tid - (tid / 6) * 6;
        int s1 = s + 1;
        float v = (e == 0) ? obs[row * 20 + s1] : (e == 1) ? obs[row * 20 + 10 + s1]
                : (e == 2) ? dimx[row * 10 + s1] : (e == 3) ? dimy[row * 10 + s1]
                : (e == 4) ? psi[row * 10 + s1] : 1.0f;
        HaugN[(size_t)row * 288 + 256 + e] = f2bf(v);
      }
      gridbar(bar, 256u * (unsigned)(s + 1));
    }
  }

  // ======== MLP1: block = 32 rows x 128 cols (final state in HaugA) ========
  {
    unsigned short* As = (unsigned short*)smem;  // 16 KB
    const int m0 = (bid >> 2) * 32, c0 = (bid & 3) * 128;
    #pragma unroll
    for (int r = 0; r < 4; ++r) {
      int j = tid + 256 * r;
      int tile = j >> 6, q = j & 63, ci = q >> 2, ks = q & 3;
      int mi = tile >> 3, kc = tile & 7;
      const unsigned short* src = HaugA + (size_t)(m0 + mi * 16 + ci) * 288 + kc * 32 + ks * 8;
      *(int4*)&As[tile * 512 + q * 8] = *(const int4*)src;
    }
    __syncthreads();
    const int foff = (l15 * 4 + g4) * 8;
    f32x4 acc[2][2];
    #pragma unroll
    for (int a = 0; a < 2; ++a)
      #pragma unroll
      for (int b = 0; b < 2; ++b) acc[a][b] = (f32x4){0.f,0.f,0.f,0.f};
    #pragma unroll
    for (int kc = 0; kc < 8; ++kc) {
      bf16x8 a0 = *(const bf16x8*)&As[(0 * 8 + kc) * 512 + foff];
      bf16x8 a1 = *(const bf16x8*)&As[(1 * 8 + kc) * 512 + foff];
      int kk = kc * 32 + g4 * 8;
      #pragma unroll
      for (int nt = 0; nt < 2; ++nt) {
        int col = c0 + w * 32 + nt * 16 + l15;
        bf16x8 b = *(const bf16x8*)&W1T[(size_t)col * 256 + kk];
        acc[0][nt] = MFMA(a0, b, acc[0][nt], 0, 0, 0);
        acc[1][nt] = MFMA(a1, b, acc[1][nt], 0, 0, 0);
      }
    }
    #pragma unroll
    for (int mi = 0; mi < 2; ++mi)
      #pragma unroll
      for (int nt = 0; nt < 2; ++nt) {
        int col = c0 + w * 32 + nt * 16 + l15;
        float bb = b1[col];
        #pragma unroll
        for (int rg = 0; rg < 4; ++rg) {
          int row = m0 + mi * 16 + g4 * 4 + rg;
          float v = fmaxf(acc[mi][nt][rg] + bb, 0.f);
          acts[(size_t)row * 512 + col] = f2bf(v);
        }
      }
    gridbar(bar, 256u * 11u);
  }

  // ======== MLP2: block = 8 rows ========
  {
    unsigned short* Ablk = (unsigned short*)smem;          // 8*520*2 = 8320 B
    float* W2s = (float*)(smem + 8320);                    // 512*22*4 = 45056 B
    const int m0 = bid * 8;
    __syncthreads();
    for (int i = tid; i < 4096; i += 256) {
      int r = i >> 9, k = i & 511;
      Ablk[r * 520 + k] = acts[(size_t)(m0 + r) * 512 + k];
    }
    for (int i = tid; i < 11264; i += 256) W2s[i] = W2[i];
    __syncthreads();
    if (tid < 176) {
      int row = tid / 22, col = tid - (tid / 22) * 22;
      float s = b2[col];
      const unsigned short* ap = &Ablk[row * 520];
      for (int k = 0; k < 512; ++k) s += bf2f(ap[k]) * W2s[k * 22 + col];
      lam[(size_t)(m0 + row) * 22 + col] = s;
    }
  }
}

// ---------------- ADMM solver: 256 thr, circle-split, 3 barriers/iter ----------------
__global__ __launch_bounds__(256) void solver(
    const float* __restrict__ ise, const float* __restrict__ goal,
    const float* __restrict__ obs, const float* __restrict__ psi,
    const float* __restrict__ dimx, const float* __restrict__ dimy,
    const float* __restrict__ yub, const float* __restrict__ ylb,
    const float* __restrict__ lam, const float* __restrict__ kkt,
    const float* __restrict__ Gxm, const float* __restrict__ Gym,
    const float* __restrict__ Mxm, const float* __restrict__ Mym,
    const float* __restrict__ sums, float* __restrict__ out)
{
  __shared__ __align__(16) float Pt[3][11][108];
  __shared__ __align__(16) float red[7][108];
  __shared__ __align__(16) float red2[2][108];
  __shared__ float redout[7][11];
  __shared__ float cx[11], cy[11], lx[11], ly[11], cx0[11], cy0[11];
  __shared__ float kxB[11], kyB[11], hx[11], hy[11];
  __shared__ float rhsx[15], rhsy[14];
  __shared__ float xc[30], yc[30], sa_[10], sb_[10], sab[10], sab2[10];

  const int b = blockIdx.x;
  const int tid = threadIdx.x;

  if (tid < 100) {
    float t = tid * (1.0f / 99.0f);
    float tjm2 = 0.f, tjm1 = 0.f, tj = 1.f;
    #pragma unroll
    for (int j = 0; j < 11; ++j) {
      Pt[0][j][tid] = tj;
      Pt[1][j][tid] = 0.1f * (float)j * tjm1;
      Pt[2][j][tid] = 0.01f * (float)(j * (j - 1)) * tjm2;
      tjm2 = tjm1; tjm1 = tj; tj *= t;
    }
  }
  if (tid < 10) {
    int o = tid;
    float xo = obs[b * 20 + o], yo = obs[b * 20 + 10 + o];
    float dx = dimx[b * 10 + o], dy = dimy[b * 10 + o], ps = psi[b * 10 + o];
    float sp, cp;
    __sincosf(ps, &sp, &cp);
    float r1 = 0.5f * (dx - dy);
    xc[o * 3] = xo; xc[o * 3 + 1] = xo + r1 * cp; xc[o * 3 + 2] = xo - r1 * cp;
    yc[o * 3] = yo; yc[o * 3 + 1] = yo + r1 * sp; yc[o * 3 + 2] = yo - r1 * sp;
    float rad = 0.5f * dy;
    float av = 3.2f + rad, bv = 1.7f + rad;
    sa_[o] = av; sb_[o] = bv; sab[o] = av * bv; sab2[o] = av * bv * av * bv;
  }
  if (tid < 11) { lx[tid] = lam[b * 22 + tid]; ly[tid] = lam[b * 22 + 11 + tid]; }
  const float vx0 = ise[b * 6 + 2], vy0 = ise[b * 6 + 3];
  if (tid == 0) {
    float x0 = ise[b * 6 + 0], y0 = ise[b * 6 + 1];
    float ax0 = ise[b * 6 + 4], ay0 = ise[b * 6 + 5];
    rhsx[11] = x0; rhsx[12] = vx0; rhsx[13] = ax0; rhsx[14] = goal[b * 2 + 0];
    rhsy[11] = y0; rhsy[12] = vy0; rhsy[13] = ay0;
  }
  {
    float vdes = sqrtf(vx0 * vx0 + vy0 * vy0);
    float gy = goal[b * 2 + 1];
    if (tid < 11) { rhsx[tid] = 2.f * vdes * sums[11 + tid]; rhsy[tid] = gy * sums[tid]; }
  }
  const float yU = yub[b], yL = ylb[b];
  __syncthreads();
  if (tid < 11) {
    const float* K = kkt + 2 * 176 + tid * 16;
    float s = 0.f;
    #pragma unroll
    for (int j = 0; j < 15; ++j) s += K[j] * rhsx[j];
    cx0[tid] = s; cx[tid] = s;
    const float* Kx = kkt + tid * 16;
    float kb = 0.f;
    #pragma unroll
    for (int c = 0; c < 4; ++c) kb += Kx[11 + c] * rhsx[11 + c];
    kxB[tid] = kb;
  } else if (tid >= 16 && tid < 27) {
    int i = tid - 16;
    const float* K = kkt + 3 * 176 + i * 16;
    float s = 0.f;
    #pragma unroll
    for (int j = 0; j < 14; ++j) s += K[j] * rhsy[j];
    cy0[i] = s; cy[i] = s;
    const float* Ky = kkt + 176 + i * 16;
    float kb = 0.f;
    #pragma unroll
    for (int c = 0; c < 3; ++c) kb += Ky[11 + c] * rhsy[11 + c];
    kyB[i] = kb;
  }
  __syncthreads();
  if (tid < 11) {
    float s = cx0[tid];
    #pragma unroll
    for (int i = 0; i < 11; ++i) s += Mxm[tid * 16 + i] * kxB[i];
    hx[tid] = s;
  } else if (tid >= 16 && tid < 27) {
    int j = tid - 16;
    float s = cy0[j];
    #pragma unroll
    for (int i = 0; i < 11; ++i) s += Mym[j * 16 + i] * kyB[i];
    hy[j] = s;
  }
  __syncthreads();

  for (int it = 0; it < 5; ++it) {
    // ---- phase 1: lanes 0-99 = poly + circles 0-14 + v/a/lane; 128-227 = poly(x,y) + circles 15-29
    if (tid < 100) {
      float t = tid * (1.0f / 99.0f);
      float x = 0, y = 0, xd = 0, yd = 0, xdd = 0, ydd = 0;
      {
        float tjm2 = 0, tjm1 = 0, tj = 1;
        #pragma unroll
        for (int j = 0; j < 11; ++j) {
          float cj = cx[j], dj = cy[j];
          x += cj * tj; y += dj * tj;
          float pd = 0.1f * (float)j * tjm1;
          xd += cj * pd; yd += dj * pd;
          float pdd = 0.01f * (float)(j * (j - 1)) * tjm2;
          xdd += cj * pdd; ydd += dj * pdd;
          tjm2 = tjm1; tjm1 = tj; tj *= t;
        }
      }
      float Sbx = 0.f, Sby = 0.f;
      for (int oi = 0; oi < 5; ++oi) {
        float A = sa_[oi], B = sb_[oi], AB = sab[oi], AB2 = sab2[oi];
        #pragma unroll
        for (int cc = 0; cc < 3; ++cc) {
          int o = oi * 3 + cc;
          float xcc = xc[o], ycc = yc[o];
          float wc = x - xcc, wsv = y - ycc;
          float p = wsv * A, q = wc * B;
          float h2 = p * p + q * q;
          float rin = rsqrtf(h2 + 1e-20f);
          float sc = AB * rin;
          bool outside = h2 >= AB2;
          Sbx += outside ? x : fmaf(wc, sc, xcc);
          Sby += outside ? y : fmaf(wsv, sc, ycc);
        }
      }
      bool clipv = (xd <= 0.f) || (fabsf(yd) > xd * 0.43463135f);
      float cv, sv;
      if (clipv) { cv = 0.91712081f; sv = copysignf(0.39860934f, yd); }
      else { float ri = rsqrtf(fmaxf(xd * xd + yd * yd, 1e-24f)); cv = xd * ri; sv = yd * ri; }
      float dv = fminf(fmaxf(xd * cv + yd * sv, 0.001f), 18.f);
      float qa = xdd + 1e-4f, pa = ydd + 1e-4f;
      float ria = rsqrtf(pa * pa + qa * qa + 1e-30f);
      float caa = qa * ria, saa = pa * ria;
      float da = fminf(fmaxf(xdd * caa + ydd * saa, 0.f), 6.f);
      red[0][tid] = Sbx; red[1][tid] = Sby;
      red[2][tid] = dv * cv; red[3][tid] = dv * sv;
      red[4][tid] = da * caa; red[5][tid] = da * saa;
      red[6][tid] = fminf(y, yU) - fminf(-y, -yL);
    } else if (tid >= 128 && tid < 228) {
      int t2 = tid - 128;
      float t = t2 * (1.0f / 99.0f);
      float x = 0, y = 0;
      {
        float tj = 1;
        #pragma unroll
        for (int j = 0; j < 11; ++j) { x += cx[j] * tj; y += cy[j] * tj; tj *= t; }
      }
      float Sbx = 0.f, Sby = 0.f;
      for (int oi = 5; oi < 10; ++oi) {
        float A = sa_[oi], B = sb_[oi], AB = sab[oi], AB2 = sab2[oi];
        #pragma unroll
        for (int cc = 0; cc < 3; ++cc) {
          int o = oi * 3 + cc;
          float xcc = xc[o], ycc = yc[o];
          float wc = x - xcc, wsv = y - ycc;
          float p = wsv * A, q = wc * B;
          float h2 = p * p + q * q;
          float rin = rsqrtf(h2 + 1e-20f);
          float sc = AB * rin;
          bool outside = h2 >= AB2;
          Sbx += outside ? x : fmaf(wc, sc, xcc);
          Sby += outside ? y : fmaf(wsv, sc, ycc);
        }
      }
      red2[0][t2] = Sbx; red2[1][t2] = Sby;
    }
    __syncthreads();
    // ---- phase 2: 7x(100->11) reduction (rows 0,1 fuse the two partials) ----
    if (tid < 77) {
      int a = tid / 11, j = tid - a * 11;
      int wt = (a < 2) ? 0 : (a < 4) ? 1 : (a < 6) ? 2 : 0;
      const float4* rp = (const float4*)(&red[a][0]);
      const float4* wp = (const float4*)(&Pt[wt][j][0]);
      float s = 0.f;
      if (a < 2) {
        const float4* r2p = (const float4*)(&red2[a][0]);
        #pragma unroll
        for (int k = 0; k < 25; ++k) {
          float4 rv = rp[k], r2 = r2p[k], wv = wp[k];
          s += (rv.x + r2.x) * wv.x + (rv.y + r2.y) * wv.y
             + (rv.z + r2.z) * wv.z + (rv.w + r2.w) * wv.w;
        }
      } else {
        #pragma unroll
        for (int k = 0; k < 25; ++k) {
          float4 rv = rp[k], wv = wp[k];
          s += rv.x * wv.x + rv.y * wv.y + rv.z * wv.z + rv.w * wv.w;
        }
      }
      redout[a][j] = s;
    }
    __syncthreads();
    // ---- phase 3+4 merged: rhs built inline; c and lambda via K/G ----
    if (tid < 11) {
      const float* K = kkt + tid * 16;
      const float* G = Gxm + tid * 16;
      float sc = kxB[tid], sl = -hx[tid];
      #pragma unroll
      for (int i = 0; i < 11; ++i) {
        float r = lx[i] + cx0[i] + redout[0][i] + redout[2][i] + redout[4][i];
        sc += K[i] * r;
        sl += G[i] * r;
      }
      cx[tid] = sc; lx[tid] = sl;
    } else if (tid >= 16 && tid < 27) {
      int j = tid - 16;
      const float* K = kkt + 176 + j * 16;
      const float* G = Gym + j * 16;
      float sc = kyB[j], sl = -hy[j];
      #pragma unroll
      for (int i = 0; i < 11; ++i) {
        float r = ly[i] + cy0[i] + redout[1][i] + redout[3][i] + redout[5][i] + redout[6][i];
        sc += K[i] * r;
        sl += G[i] * r;
      }
      cy[j] = sc; ly[j] = sl;
    }
    __syncthreads();
  }
  if (tid < 11) out[b * 22 + tid] = cx[tid];
  else if (tid >= 16 && tid < 27) out[b * 22 + 11 + (tid - 16)] = cy[tid - 16];
}

extern "C" void kernel_launch(void* const* d_in, const int* in_sizes, int n_in,
                              void* d_out, int out_size, void* d_ws, size_t ws_size,
                              hipStream_t stream) {
  const float* ise  = (const float*)d_in[0];
  const float* goal = (const float*)d_in[1];
  const float* obs  = (const float*)d_in[2];
  const float* psi  = (const float*)d_in[3];
  const float* dimx = (const float*)d_in[4];
  const float* dimy = (const float*)d_in[5];
  const float* yub  = (const float*)d_in[6];
  const float* ylb  = (const float*)d_in[7];
  const float* Wih  = (const float*)d_in[8];
  const float* Whh  = (const float*)d_in[9];
  const float* gb   = (const float*)d_in[10];
  const float* h0   = (const float*)d_in[11];
  const float* W1   = (const float*)d_in[12];
  const float* b1   = (const float*)d_in[13];
  const float* W2   = (const float*)d_in[14];
  const float* b2   = (const float*)d_in[15];

  char* ws = (char*)d_ws;
  unsigned short* Waug  = (unsigned short*)(ws + WS_WAUG);
  unsigned short* W1T   = (unsigned short*)(ws + WS_W1T);
  unsigned short* HaugA = (unsigned short*)(ws + WS_HAUGA);
  unsigned short* HaugB = (unsigned short*)(ws + WS_HAUGB);
  float* Hf32 = (float*)(ws + WS_HF32);
  unsigned short* acts = (unsigned short*)(ws + WS_ACTS);
  float* lamb = (float*)(ws + WS_LAM);
  float* kkt  = (float*)(ws + WS_KKT);
  float* Gxm  = (float*)(ws + WS_GX);
  float* Gym  = (float*)(ws + WS_GY);
  float* Mxm  = (float*)(ws + WS_MX);
  float* Mym  = (float*)(ws + WS_MY);
  float* sums = (float*)(ws + WS_SUMS);
  unsigned int* bar = (unsigned int*)(ws + WS_BAR);

  prep<<<3892, 256, 0, stream>>>(Whh, Wih, gb, W1, h0, obs, dimx, dimy, psi,
                                 Waug, W1T, HaugA, HaugB, kkt, Gxm, Gym, Mxm, Mym,
                                 sums, bar);
  nn_all<<<256, 256, 0, stream>>>(Waug, HaugA, HaugB, Hf32, h0,
                                  obs, dimx, dimy, psi, W1T, b1, W2, b2,
                                  acts, lamb, bar);
  solver<<<2048, 256, 0, stream>>>(ise, goal, obs, psi, dimx, dimy, yub, ylb,
                                   lamb, kkt, Gxm, Gym, Mxm, Mym, sums, (float*)d_out);
  (void)in_sizes; (void)n_in; (void)out_size; (void)ws_size;
}

// Round 8
// 262.867 us; speedup vs baseline: 3.6596x; 3.6596x over previous
//
#include <hip/hip_runtime.h>
#include <math.h>

typedef short bf16x8 __attribute__((ext_vector_type(8)));
typedef float f32x4 __attribute__((ext_vector_type(4)));

__device__ __forceinline__ unsigned short f2bf(float x) {
  union { float f; unsigned u; } v; v.f = x;
  unsigned r = v.u + 0x7FFFu + ((v.u >> 16) & 1u);
  return (unsigned short)(r >> 16);
}
__device__ __forceinline__ float bf2f(unsigned short h) {
  union { unsigned u; float f; } v; v.u = ((unsigned)h) << 16; return v.f;
}

// ---------------- workspace layout (bytes) ----------------
#define WS_WAUG  0u         // [768][288] bf16 (Whh^T | Wih^T | bias | 0)
#define WS_W1T   442368u    // [512][256] bf16
#define WS_HAUGA 704512u    // [2048][288] bf16  (h bf16 | feats | 1 | 0)
#define WS_HAUGB 1884160u   // [2048][288] bf16
#define WS_HF32  3063808u   // [2048][256] f32
#define WS_LAM   5160960u   // [2048][22] f32
#define WS_KKT   5341184u   // 4 x [11][16] f32
#define WS_GX    5344000u   // [11][16] f32
#define WS_GY    5344704u   // [11][16] f32
#define WS_MX    5345408u   // [11][16] f32
#define WS_MY    5346112u   // [11][16] f32
#define WS_SUMS  5346816u   // sumP[11], sumPDOT[11]
#define WS_W2T   5346944u   // [32][512] bf16 (cols 22..31 zero)

// ---------------- prep: KKT inverses + M/G (blocks 0-3) + weight/state packing ----------------
__global__ __launch_bounds__(256) void prep(
    const float* __restrict__ Whh, const float* __restrict__ Wih,
    const float* __restrict__ gb, const float* __restrict__ W1,
    const float* __restrict__ W2, const float* __restrict__ h0,
    const float* __restrict__ obs, const float* __restrict__ dimx,
    const float* __restrict__ dimy, const float* __restrict__ psi,
    unsigned short* __restrict__ Waug, unsigned short* __restrict__ W1T,
    unsigned short* __restrict__ W2T,
    unsigned short* __restrict__ HaugA, unsigned short* __restrict__ HaugB,
    float* __restrict__ kkt_out, float* __restrict__ Gx_out,
    float* __restrict__ Gy_out, float* __restrict__ Mx_out,
    float* __restrict__ My_out, float* __restrict__ sums_out)
{
  __shared__ double S[21];
  __shared__ double aug[15][32];
  __shared__ double fbuf[15];
  __shared__ double Md[11][11];
  if (blockIdx.x < 4) {
    const int mat = blockIdx.x;
    const int n = (mat == 0 || mat == 2) ? 15 : 14;
    const int twoN = 2 * n;
    if (threadIdx.x == 0) {
      for (int m = 0; m < 21; ++m) S[m] = 0.0;
      for (int s = 0; s < 100; ++s) {
        double t = s * (1.0 / 99.0);
        double p = 1.0;
        for (int m = 0; m < 21; ++m) { S[m] += p; p *= t; }
      }
    }
    __syncthreads();
    for (int idx = threadIdx.x; idx < n * twoN; idx += 256) {
      int r = idx / twoN, c = idx % twoN;
      double v;
      if (c >= n) v = (c - n == r) ? 1.0 : 0.0;
      else if (r < 11 && c < 11) {
        double ptp = S[r + c];
        double pdp = (r >= 1 && c >= 1) ? ((double)(r * c) / 100.0) * S[r + c - 2] : 0.0;
        double pddp = (r >= 2 && c >= 2) ? ((double)(r*(r-1)) * (double)(c*(c-1)) / 10000.0) * S[r + c - 4] : 0.0;
        double dg = (r == c) ? 1.0 : 0.0;
        if (mat == 0)      v = 21.0*dg + 30.0*ptp + pdp + pddp;
        else if (mat == 1) v = 21.0*dg + 32.0*ptp + pdp + pddp;
        else if (mat == 2) v = 20.0*dg + 2.0*pdp;
        else               v = 20.0*dg + 2.0*pdp + ptp;
      } else if (r >= 11 && c >= 11) v = 0.0;
      else {
        int ar = (r >= 11) ? (r - 11) : (c - 11);
        int ac = (r >= 11) ? c : r;
        v = (ar == 0) ? ((ac == 0) ? 1.0 : 0.0)
          : (ar == 1) ? ((ac == 1) ? 0.1 : 0.0)
          : (ar == 2) ? ((ac == 2) ? 0.02 : 0.0)
          : 1.0;
      }
      aug[r][c] = v;
    }
    __syncthreads();
    for (int p = 0; p < n; ++p) {
      double pv = aug[p][p];
      __syncthreads();
      double inv = 1.0 / pv;
      for (int c = threadIdx.x; c < twoN; c += 256) aug[p][c] *= inv;
      __syncthreads();
      if (threadIdx.x < n) fbuf[threadIdx.x] = aug[threadIdx.x][p];
      __syncthreads();
      for (int idx = threadIdx.x; idx < n * twoN; idx += 256) {
        int r = idx / twoN, c = idx % twoN;
        if (r != p) aug[r][c] -= fbuf[r] * aug[p][c];
      }
      __syncthreads();
    }
    for (int idx = threadIdx.x; idx < 11 * n; idx += 256) {
      int r = idx / n, c = idx % n;
      kkt_out[mat * 176 + r * 16 + c] = (float)aug[r][n + c];
    }
    if (mat < 2) {
      if (threadIdx.x < 121) {
        int j = threadIdx.x / 11, i = threadIdx.x % 11;
        double m = 30.0 * S[j + i];
        if (j >= 1 && i >= 1) m += ((double)(j * i) / 100.0) * S[j + i - 2];
        if (j >= 2 && i >= 2) m += ((double)(j*(j-1)) * (double)(i*(i-1)) / 10000.0) * S[j + i - 4];
        if (mat == 1) m += 2.0 * S[j + i];
        Md[j][i] = m;
      }
      __syncthreads();
      if (threadIdx.x < 121) {
        int j = threadIdx.x / 11, i = threadIdx.x % 11;
        double g = (j == i) ? 1.0 : 0.0;
        for (int k = 0; k < 11; ++k) g -= Md[j][k] * aug[k][n + i];
        if (mat == 0) { Gx_out[j * 16 + i] = (float)g; Mx_out[j * 16 + i] = (float)Md[j][i]; }
        else          { Gy_out[j * 16 + i] = (float)g; My_out[j * 16 + i] = (float)Md[j][i]; }
      }
    }
    if (mat == 0 && threadIdx.x < 11) {
      int j = threadIdx.x;
      sums_out[j] = (float)S[j];
      sums_out[11 + j] = (j >= 1) ? (float)((double)j / 10.0 * S[j - 1]) : 0.f;
    }
    return;
  }
  int idx = (blockIdx.x - 4) * 256 + threadIdx.x;
  if (idx < 221184) {           // Waug[col][k], k in [0,288)
    int col = idx / 288, k = idx - col * 288;
    float v;
    if (k < 256)       v = Whh[k * 768 + col];
    else if (k < 261)  v = Wih[(k - 256) * 768 + col];
    else if (k == 261) v = gb[col];
    else               v = 0.f;
    Waug[idx] = f2bf(v);
  } else if (idx < 352256) {    // W1T[col][k]
    int j = idx - 221184;
    int col = j >> 8, k = j & 255;
    W1T[j] = f2bf(W1[k * 512 + col]);
  } else if (idx < 942080) {    // HaugA full init
    int j = idx - 352256;
    int row = j / 288, k = j - row * 288;
    float v;
    if (k < 256)       v = h0[k];
    else if (k == 256) v = obs[row * 20 + 0];
    else if (k == 257) v = obs[row * 20 + 10];
    else if (k == 258) v = dimx[row * 10 + 0];
    else if (k == 259) v = dimy[row * 10 + 0];
    else if (k == 260) v = psi[row * 10 + 0];
    else if (k == 261) v = 1.0f;
    else               v = 0.f;
    HaugA[row * 288 + k] = f2bf(v);
  } else if (idx < 995328) {    // HaugB: constant tail zeros (k=262..287)
    int j = idx - 942080;
    int row = j / 26, k = 262 + (j - row * 26);
    HaugB[row * 288 + k] = 0;
  } else if (idx < 1011712) {   // W2T[col][k] (32x512, cols>=22 zero)
    int j = idx - 995328;
    int col = j >> 9, k = j & 511;
    W2T[j] = f2bf(col < 22 ? W2[k * 22 + col] : 0.f);
  }
}

// ---------------- GRU step: 512 blocks, direct-from-L2 fragments, no LDS ----------------
#define MFMA __builtin_amdgcn_mfma_f32_16x16x32_bf16
__global__ __launch_bounds__(256) void gru_step(
    const unsigned short* __restrict__ Waug,
    const unsigned short* __restrict__ HaugC, unsigned short* __restrict__ HaugN,
    float* __restrict__ Hf32, const float* __restrict__ h0,
    const float* __restrict__ obs, const float* __restrict__ dimx,
    const float* __restrict__ dimy, const float* __restrict__ psi,
    int s)
{
  const int tid = threadIdx.x;
  const int m0 = blockIdx.x * 32;
  const int c0 = blockIdx.y * 32;
  const int lane = tid & 63, w = tid >> 6;
  const int l15 = lane & 15, g4 = lane >> 4;
  const int mi = w >> 1, cg = w & 1;

  const unsigned short* Arow = HaugC + (size_t)(m0 + mi * 16 + l15) * 288 + g4 * 8;
  const unsigned short* Bcol = Waug + (size_t)(c0 + cg * 16 + l15) * 288 + g4 * 8;

  f32x4 accz = {0.f,0.f,0.f,0.f}, accr = {0.f,0.f,0.f,0.f};
  f32x4 anh = {0.f,0.f,0.f,0.f}, anx = {0.f,0.f,0.f,0.f};

  #pragma unroll
  for (int kc = 0; kc < 9; ++kc) {
    bf16x8 a  = *(const bf16x8*)(Arow + kc * 32);
    bf16x8 bz = *(const bf16x8*)(Bcol + kc * 32);
    bf16x8 br = *(const bf16x8*)(Bcol + 256 * 288 + kc * 32);
    bf16x8 bn = *(const bf16x8*)(Bcol + 512 * 288 + kc * 32);
    accz = MFMA(a, bz, accz, 0, 0, 0);
    accr = MFMA(a, br, accr, 0, 0, 0);
    if (kc < 8) anh = MFMA(a, bn, anh, 0, 0, 0);
    else        anx = MFMA(a, bn, anx, 0, 0, 0);
  }

  const int colh = c0 + cg * 16 + l15;
  float h0c = (s == 0) ? h0[colh] : 0.f;
  #pragma unroll
  for (int rg = 0; rg < 4; ++rg) {
    int row = m0 + mi * 16 + g4 * 4 + rg;
    float hold = (s == 0) ? h0c : Hf32[(size_t)row * 256 + colh];
    float z = 1.f / (1.f + __expf(-accz[rg]));
    float rr = 1.f / (1.f + __expf(-accr[rg]));
    float nn = tanhf(anx[rg] + rr * anh[rg]);
    float hnew = (1.f - z) * nn + z * hold;
    Hf32[(size_t)row * 256 + colh] = hnew;
    HaugN[(size_t)row * 288 + colh] = f2bf(hnew);
  }
  if (blockIdx.y == 0 && s < 9 && tid < 192) {
    int row = m0 + tid / 6, e = tid - (tid / 6) * 6;
    int s1 = s + 1;
    float v = (e == 0) ? obs[row * 20 + s1] : (e == 1) ? obs[row * 20 + 10 + s1]
            : (e == 2) ? dimx[row * 10 + s1] : (e == 3) ? dimy[row * 10 + s1]
            : (e == 4) ? psi[row * 10 + s1] : 1.0f;
    HaugN[(size_t)row * 288 + 256 + e] = f2bf(v);
  }
}

// ---------------- fused MLP: 128 blocks x 16 rows; acts stay in LDS ----------------
__global__ __launch_bounds__(256) void mlp_fused(
    const unsigned short* __restrict__ Haug, const unsigned short* __restrict__ W1T,
    const float* __restrict__ b1, const unsigned short* __restrict__ W2T,
    const float* __restrict__ b2, float* __restrict__ lam)
{
  __shared__ __align__(16) unsigned short As[4096];    // 8 tiles x 512 (16 rows x K=256)
  __shared__ __align__(16) unsigned short Acts[8192];  // 16 tiles x 512 (16 rows x K=512)
  const int tid = threadIdx.x;
  const int m0 = blockIdx.x * 16;
  const int lane = tid & 63, w = tid >> 6, l15 = lane & 15, g4 = lane >> 4;

  #pragma unroll
  for (int r = 0; r < 2; ++r) {
    int j = tid + 256 * r;
    int tile = j >> 6, q = j & 63, ci = q >> 2, ks = q & 3;
    const unsigned short* src = Haug + (size_t)(m0 + ci) * 288 + tile * 32 + ks * 8;
    *(int4*)&As[tile * 512 + q * 8] = *(const int4*)src;
  }
  __syncthreads();
  const int foff = (l15 * 4 + g4) * 8;

  // MLP1: wave w covers cols w*128..+128
  f32x4 acc[8];
  #pragma unroll
  for (int nt = 0; nt < 8; ++nt) acc[nt] = (f32x4){0.f,0.f,0.f,0.f};
  #pragma unroll
  for (int kc = 0; kc < 8; ++kc) {
    bf16x8 a = *(const bf16x8*)&As[kc * 512 + foff];
    int kk = kc * 32 + g4 * 8;
    #pragma unroll
    for (int nt = 0; nt < 8; ++nt) {
      int col = w * 128 + nt * 16 + l15;
      bf16x8 b = *(const bf16x8*)&W1T[(size_t)col * 256 + kk];
      acc[nt] = MFMA(a, b, acc[nt], 0, 0, 0);
    }
  }
  #pragma unroll
  for (int nt = 0; nt < 8; ++nt) {
    int col = w * 128 + nt * 16 + l15;
    float bb = b1[col];
    int tile = col >> 5, sub = (col >> 3) & 3, e = col & 7;
    #pragma unroll
    for (int rg = 0; rg < 4; ++rg) {
      int row = g4 * 4 + rg;
      float v = fmaxf(acc[nt][rg] + bb, 0.f);
      Acts[tile * 512 + (row * 4 + sub) * 8 + e] = f2bf(v);
    }
  }
  __syncthreads();

  // MLP2: waves 0,1 cover cols 0..31 (22 used), K=512
  if (w < 2) {
    int col = w * 16 + l15;
    f32x4 a2 = {0.f,0.f,0.f,0.f};
    #pragma unroll
    for (int kc = 0; kc < 16; ++kc) {
      bf16x8 a = *(const bf16x8*)&Acts[kc * 512 + foff];
      bf16x8 b = *(const bf16x8*)&W2T[(size_t)col * 512 + kc * 32 + g4 * 8];
      a2 = MFMA(a, b, a2, 0, 0, 0);
    }
    if (col < 22) {
      float bb = b2[col];
      #pragma unroll
      for (int rg = 0; rg < 4; ++rg)
        lam[(size_t)(m0 + g4 * 4 + rg) * 22 + col] = a2[rg] + bb;
    }
  }
}

// ---------------- ADMM solver: 128 thr, G/M-folded, 3 barriers/iter ----------------
__global__ __launch_bounds__(128) void solver(
    const float* __restrict__ ise, const float* __restrict__ goal,
    const float* __restrict__ obs, const float* __restrict__ psi,
    const float* __restrict__ dimx, const float* __restrict__ dimy,
    const float* __restrict__ yub, const float* __restrict__ ylb,
    const float* __restrict__ lam, const float* __restrict__ kkt,
    const float* __restrict__ Gxm, const float* __restrict__ Gym,
    const float* __restrict__ Mxm, const float* __restrict__ Mym,
    const float* __restrict__ sums, float* __restrict__ out)
{
  __shared__ __align__(16) float Pt[3][11][108];
  __shared__ __align__(16) float red[7][108];
  __shared__ float redout[7][11];
  __shared__ float cx[11], cy[11], lx[11], ly[11], cx0[11], cy0[11];
  __shared__ float kxB[11], kyB[11], hx[11], hy[11];
  __shared__ float rhsx[15], rhsy[14];
  __shared__ float xc[30], yc[30], sa_[10], sb_[10], sab[10], sab2[10];

  const int b = blockIdx.x;
  const int tid = threadIdx.x;

  if (tid < 100) {
    float t = tid * (1.0f / 99.0f);
    float tjm2 = 0.f, tjm1 = 0.f, tj = 1.f;
    #pragma unroll
    for (int j = 0; j < 11; ++j) {
      Pt[0][j][tid] = tj;
      Pt[1][j][tid] = 0.1f * (float)j * tjm1;
      Pt[2][j][tid] = 0.01f * (float)(j * (j - 1)) * tjm2;
      tjm2 = tjm1; tjm1 = tj; tj *= t;
    }
  }
  if (tid < 10) {
    int o = tid;
    float xo = obs[b * 20 + o], yo = obs[b * 20 + 10 + o];
    float dx = dimx[b * 10 + o], dy = dimy[b * 10 + o], ps = psi[b * 10 + o];
    float sp, cp;
    __sincosf(ps, &sp, &cp);
    float r1 = 0.5f * (dx - dy);
    xc[o * 3] = xo; xc[o * 3 + 1] = xo + r1 * cp; xc[o * 3 + 2] = xo - r1 * cp;
    yc[o * 3] = yo; yc[o * 3 + 1] = yo + r1 * sp; yc[o * 3 + 2] = yo - r1 * sp;
    float rad = 0.5f * dy;
    float av = 3.2f + rad, bv = 1.7f + rad;
    sa_[o] = av; sb_[o] = bv; sab[o] = av * bv; sab2[o] = av * bv * av * bv;
  }
  if (tid < 11) { lx[tid] = lam[b * 22 + tid]; ly[tid] = lam[b * 22 + 11 + tid]; }
  const float vx0 = ise[b * 6 + 2], vy0 = ise[b * 6 + 3];
  if (tid == 0) {
    float x0 = ise[b * 6 + 0], y0 = ise[b * 6 + 1];
    float ax0 = ise[b * 6 + 4], ay0 = ise[b * 6 + 5];
    rhsx[11] = x0; rhsx[12] = vx0; rhsx[13] = ax0; rhsx[14] = goal[b * 2 + 0];
    rhsy[11] = y0; rhsy[12] = vy0; rhsy[13] = ay0;
  }
  {
    float vdes = sqrtf(vx0 * vx0 + vy0 * vy0);
    float gy = goal[b * 2 + 1];
    if (tid < 11) { rhsx[tid] = 2.f * vdes * sums[11 + tid]; rhsy[tid] = gy * sums[tid]; }
  }
  const float yU = yub[b], yL = ylb[b];
  __syncthreads();
  if (tid < 11) {
    const float* K = kkt + 2 * 176 + tid * 16;
    float s = 0.f;
    #pragma unroll
    for (int j = 0; j < 15; ++j) s += K[j] * rhsx[j];
    cx0[tid] = s; cx[tid] = s;
    const float* Kx = kkt + tid * 16;
    float kb = 0.f;
    #pragma unroll
    for (int c = 0; c < 4; ++c) kb += Kx[11 + c] * rhsx[11 + c];
    kxB[tid] = kb;
  } else if (tid >= 16 && tid < 27) {
    int i = tid - 16;
    const float* K = kkt + 3 * 176 + i * 16;
    float s = 0.f;
    #pragma unroll
    for (int j = 0; j < 14; ++j) s += K[j] * rhsy[j];
    cy0[i] = s; cy[i] = s;
    const float* Ky = kkt + 176 + i * 16;
    float kb = 0.f;
    #pragma unroll
    for (int c = 0; c < 3; ++c) kb += Ky[11 + c] * rhsy[11 + c];
    kyB[i] = kb;
  }
  __syncthreads();
  if (tid < 11) {
    float s = cx0[tid];
    #pragma unroll
    for (int i = 0; i < 11; ++i) s += Mxm[tid * 16 + i] * kxB[i];
    hx[tid] = s;
  } else if (tid >= 16 && tid < 27) {
    int j = tid - 16;
    float s = cy0[j];
    #pragma unroll
    for (int i = 0; i < 11; ++i) s += Mym[j * 16 + i] * kyB[i];
    hy[j] = s;
  }
  __syncthreads();

  for (int it = 0; it < 5; ++it) {
    // ---- phase 1: per-s-point nonlinear projections ----
    if (tid < 100) {
      float t = tid * (1.0f / 99.0f);
      float x = 0, y = 0, xd = 0, yd = 0, xdd = 0, ydd = 0;
      {
        float tjm2 = 0, tjm1 = 0, tj = 1;
        #pragma unroll
        for (int j = 0; j < 11; ++j) {
          float cj = cx[j], dj = cy[j];
          x += cj * tj; y += dj * tj;
          float pd = 0.1f * (float)j * tjm1;
          xd += cj * pd; yd += dj * pd;
          float pdd = 0.01f * (float)(j * (j - 1)) * tjm2;
          xdd += cj * pdd; ydd += dj * pdd;
          tjm2 = tjm1; tjm1 = tj; tj *= t;
        }
      }
      float Sbx = 0.f, Sby = 0.f;
      for (int oi = 0; oi < 10; ++oi) {
        float A = sa_[oi], B = sb_[oi], AB = sab[oi], AB2 = sab2[oi];
        #pragma unroll
        for (int cc = 0; cc < 3; ++cc) {
          int o = oi * 3 + cc;
          float xcc = xc[o], ycc = yc[o];
          float wc = x - xcc, wsv = y - ycc;
          float p = wsv * A, q = wc * B;
          float h2 = p * p + q * q;
          float rin = rsqrtf(h2 + 1e-20f);
          float sc = AB * rin;
          bool outside = h2 >= AB2;
          Sbx += outside ? x : fmaf(wc, sc, xcc);
          Sby += outside ? y : fmaf(wsv, sc, ycc);
        }
      }
      bool clipv = (xd <= 0.f) || (fabsf(yd) > xd * 0.43463135f);
      float cv, sv;
      if (clipv) { cv = 0.91712081f; sv = copysignf(0.39860934f, yd); }
      else { float ri = rsqrtf(fmaxf(xd * xd + yd * yd, 1e-24f)); cv = xd * ri; sv = yd * ri; }
      float dv = fminf(fmaxf(xd * cv + yd * sv, 0.001f), 18.f);
      float qa = xdd + 1e-4f, pa = ydd + 1e-4f;
      float ria = rsqrtf(pa * pa + qa * qa + 1e-30f);
      float caa = qa * ria, saa = pa * ria;
      float da = fminf(fmaxf(xdd * caa + ydd * saa, 0.f), 6.f);
      red[0][tid] = Sbx; red[1][tid] = Sby;
      red[2][tid] = dv * cv; red[3][tid] = dv * sv;
      red[4][tid] = da * caa; red[5][tid] = da * saa;
      red[6][tid] = fminf(y, yU) - fminf(-y, -yL);
    }
    __syncthreads();
    // ---- phase 2: 7x(100->11) reduction ----
    if (tid < 77) {
      int a = tid / 11, j = tid - a * 11;
      int wt = (a < 2) ? 0 : (a < 4) ? 1 : (a < 6) ? 2 : 0;
      const float4* rp = (const float4*)(&red[a][0]);
      const float4* wp = (const float4*)(&Pt[wt][j][0]);
      float s = 0.f;
      #pragma unroll
      for (int k = 0; k < 25; ++k) {
        float4 rv = rp[k], wv = wp[k];
        s += rv.x * wv.x + rv.y * wv.y + rv.z * wv.z + rv.w * wv.w;
      }
      redout[a][j] = s;
    }
    __syncthreads();
    // ---- phase 3+4 merged: rhs built inline; c and lambda via K/G ----
    // (wave-0 lockstep: all loop reads of lx/ly complete before the trailing stores)
    if (tid < 11) {
      const float* K = kkt + tid * 16;
      const float* G = Gxm + tid * 16;
      float sc = kxB[tid], sl = -hx[tid];
      #pragma unroll
      for (int i = 0; i < 11; ++i) {
        float r = lx[i] + cx0[i] + redout[0][i] + redout[2][i] + redout[4][i];
        sc += K[i] * r;
        sl += G[i] * r;
      }
      cx[tid] = sc; lx[tid] = sl;
    } else if (tid >= 16 && tid < 27) {
      int j = tid - 16;
      const float* K = kkt + 176 + j * 16;
      const float* G = Gym + j * 16;
      float sc = kyB[j], sl = -hy[j];
      #pragma unroll
      for (int i = 0; i < 11; ++i) {
        float r = ly[i] + cy0[i] + redout[1][i] + redout[3][i] + redout[5][i] + redout[6][i];
        sc += K[i] * r;
        sl += G[i] * r;
      }
      cy[j] = sc; ly[j] = sl;
    }
    __syncthreads();
  }
  if (tid < 11) out[b * 22 + tid] = cx[tid];
  else if (tid >= 16 && tid < 27) out[b * 22 + 11 + (tid - 16)] = cy[tid - 16];
}

extern "C" void kernel_launch(void* const* d_in, const int* in_sizes, int n_in,
                              void* d_out, int out_size, void* d_ws, size_t ws_size,
                              hipStream_t stream) {
  const float* ise  = (const float*)d_in[0];
  const float* goal = (const float*)d_in[1];
  const float* obs  = (const float*)d_in[2];
  const float* psi  = (const float*)d_in[3];
  const float* dimx = (const float*)d_in[4];
  const float* dimy = (const float*)d_in[5];
  const float* yub  = (const float*)d_in[6];
  const float* ylb  = (const float*)d_in[7];
  const float* Wih  = (const float*)d_in[8];
  const float* Whh  = (const float*)d_in[9];
  const float* gb   = (const float*)d_in[10];
  const float* h0   = (const float*)d_in[11];
  const float* W1   = (const float*)d_in[12];
  const float* b1   = (const float*)d_in[13];
  const float* W2   = (const float*)d_in[14];
  const float* b2   = (const float*)d_in[15];

  char* ws = (char*)d_ws;
  unsigned short* Waug  = (unsigned short*)(ws + WS_WAUG);
  unsigned short* W1T   = (unsigned short*)(ws + WS_W1T);
  unsigned short* W2T   = (unsigned short*)(ws + WS_W2T);
  unsigned short* HaugA = (unsigned short*)(ws + WS_HAUGA);
  unsigned short* HaugB = (unsigned short*)(ws + WS_HAUGB);
  float* Hf32 = (float*)(ws + WS_HF32);
  float* lamb = (float*)(ws + WS_LAM);
  float* kkt  = (float*)(ws + WS_KKT);
  float* Gxm  = (float*)(ws + WS_GX);
  float* Gym  = (float*)(ws + WS_GY);
  float* Mxm  = (float*)(ws + WS_MX);
  float* Mym  = (float*)(ws + WS_MY);
  float* sums = (float*)(ws + WS_SUMS);

  prep<<<3956, 256, 0, stream>>>(Whh, Wih, gb, W1, W2, h0, obs, dimx, dimy, psi,
                                 Waug, W1T, W2T, HaugA, HaugB,
                                 kkt, Gxm, Gym, Mxm, Mym, sums);
  for (int s = 0; s < 10; ++s) {
    const unsigned short* hc = (s & 1) ? HaugB : HaugA;
    unsigned short* hn = (s & 1) ? HaugA : HaugB;
    gru_step<<<dim3(64, 8), 256, 0, stream>>>(Waug, hc, hn, Hf32, h0,
                                              obs, dimx, dimy, psi, s);
  }
  mlp_fused<<<128, 256, 0, stream>>>(HaugA, W1T, b1, W2T, b2, lamb);
  solver<<<2048, 128, 0, stream>>>(ise, goal, obs, psi, dimx, dimy, yub, ylb,
                                   lamb, kkt, Gxm, Gym, Mxm, Mym, sums, (float*)d_out);
  (void)in_sizes; (void)n_in; (void)out_size; (void)ws_size;
}

// Round 9
// 241.364 us; speedup vs baseline: 3.9856x; 1.0891x over previous
//
#include <hip/hip_runtime.h>
#include <math.h>

typedef short bf16x8 __attribute__((ext_vector_type(8)));
typedef float f32x4 __attribute__((ext_vector_type(4)));

__device__ __forceinline__ unsigned short f2bf(float x) {
  union { float f; unsigned u; } v; v.f = x;
  unsigned r = v.u + 0x7FFFu + ((v.u >> 16) & 1u);
  return (unsigned short)(r >> 16);
}
__device__ __forceinline__ float bf2f(unsigned short h) {
  union { unsigned u; float f; } v; v.u = ((unsigned)h) << 16; return v.f;
}

// ---------------- workspace layout (bytes) ----------------
#define WS_WAUG  0u         // [768][288] bf16 (Whh^T | Wih^T | bias | 0)
#define WS_W1T   442368u    // [512][256] bf16
#define WS_HAUGA 704512u    // [2048][288] bf16  (h bf16 | feats | 1 | 0)
#define WS_HAUGB 1884160u   // [2048][288] bf16
#define WS_HF32  3063808u   // [2048][256] f32
#define WS_LAM   5160960u   // [2048][22] f32
#define WS_KKT   5341184u   // 4 x [11][16] f32
#define WS_GX    5344000u   // [11][16] f32
#define WS_GY    5344704u   // [11][16] f32
#define WS_MX    5345408u   // [11][16] f32
#define WS_MY    5346112u   // [11][16] f32
#define WS_SUMS  5346816u   // sumP[11], sumPDOT[11]
#define WS_W2T   5346944u   // [32][512] bf16 (cols 22..31 zero)

// ---------------- prep: KKT inverses + M/G (blocks 0-3) + weight/state packing ----------------
__global__ __launch_bounds__(256) void prep(
    const float* __restrict__ Whh, const float* __restrict__ Wih,
    const float* __restrict__ gb, const float* __restrict__ W1,
    const float* __restrict__ W2, const float* __restrict__ h0,
    const float* __restrict__ obs, const float* __restrict__ dimx,
    const float* __restrict__ dimy, const float* __restrict__ psi,
    unsigned short* __restrict__ Waug, unsigned short* __restrict__ W1T,
    unsigned short* __restrict__ W2T,
    unsigned short* __restrict__ HaugA, unsigned short* __restrict__ HaugB,
    float* __restrict__ kkt_out, float* __restrict__ Gx_out,
    float* __restrict__ Gy_out, float* __restrict__ Mx_out,
    float* __restrict__ My_out, float* __restrict__ sums_out)
{
  __shared__ double S[21];
  __shared__ double aug[15][32];
  __shared__ double fbuf[15];
  __shared__ double Md[11][11];
  if (blockIdx.x < 4) {
    const int mat = blockIdx.x;
    const int n = (mat == 0 || mat == 2) ? 15 : 14;
    const int twoN = 2 * n;
    if (threadIdx.x == 0) {
      for (int m = 0; m < 21; ++m) S[m] = 0.0;
      for (int s = 0; s < 100; ++s) {
        double t = s * (1.0 / 99.0);
        double p = 1.0;
        for (int m = 0; m < 21; ++m) { S[m] += p; p *= t; }
      }
    }
    __syncthreads();
    for (int idx = threadIdx.x; idx < n * twoN; idx += 256) {
      int r = idx / twoN, c = idx % twoN;
      double v;
      if (c >= n) v = (c - n == r) ? 1.0 : 0.0;
      else if (r < 11 && c < 11) {
        double ptp = S[r + c];
        double pdp = (r >= 1 && c >= 1) ? ((double)(r * c) / 100.0) * S[r + c - 2] : 0.0;
        double pddp = (r >= 2 && c >= 2) ? ((double)(r*(r-1)) * (double)(c*(c-1)) / 10000.0) * S[r + c - 4] : 0.0;
        double dg = (r == c) ? 1.0 : 0.0;
        if (mat == 0)      v = 21.0*dg + 30.0*ptp + pdp + pddp;
        else if (mat == 1) v = 21.0*dg + 32.0*ptp + pdp + pddp;
        else if (mat == 2) v = 20.0*dg + 2.0*pdp;
        else               v = 20.0*dg + 2.0*pdp + ptp;
      } else if (r >= 11 && c >= 11) v = 0.0;
      else {
        int ar = (r >= 11) ? (r - 11) : (c - 11);
        int ac = (r >= 11) ? c : r;
        v = (ar == 0) ? ((ac == 0) ? 1.0 : 0.0)
          : (ar == 1) ? ((ac == 1) ? 0.1 : 0.0)
          : (ar == 2) ? ((ac == 2) ? 0.02 : 0.0)
          : 1.0;
      }
      aug[r][c] = v;
    }
    __syncthreads();
    for (int p = 0; p < n; ++p) {
      double pv = aug[p][p];
      __syncthreads();
      double inv = 1.0 / pv;
      for (int c = threadIdx.x; c < twoN; c += 256) aug[p][c] *= inv;
      __syncthreads();
      if (threadIdx.x < n) fbuf[threadIdx.x] = aug[threadIdx.x][p];
      __syncthreads();
      for (int idx = threadIdx.x; idx < n * twoN; idx += 256) {
        int r = idx / twoN, c = idx % twoN;
        if (r != p) aug[r][c] -= fbuf[r] * aug[p][c];
      }
      __syncthreads();
    }
    for (int idx = threadIdx.x; idx < 11 * n; idx += 256) {
      int r = idx / n, c = idx % n;
      kkt_out[mat * 176 + r * 16 + c] = (float)aug[r][n + c];
    }
    if (mat < 2) {
      if (threadIdx.x < 121) {
        int j = threadIdx.x / 11, i = threadIdx.x % 11;
        double m = 30.0 * S[j + i];
        if (j >= 1 && i >= 1) m += ((double)(j * i) / 100.0) * S[j + i - 2];
        if (j >= 2 && i >= 2) m += ((double)(j*(j-1)) * (double)(i*(i-1)) / 10000.0) * S[j + i - 4];
        if (mat == 1) m += 2.0 * S[j + i];
        Md[j][i] = m;
      }
      __syncthreads();
      if (threadIdx.x < 121) {
        int j = threadIdx.x / 11, i = threadIdx.x % 11;
        double g = (j == i) ? 1.0 : 0.0;
        for (int k = 0; k < 11; ++k) g -= Md[j][k] * aug[k][n + i];
        if (mat == 0) { Gx_out[j * 16 + i] = (float)g; Mx_out[j * 16 + i] = (float)Md[j][i]; }
        else          { Gy_out[j * 16 + i] = (float)g; My_out[j * 16 + i] = (float)Md[j][i]; }
      }
    }
    if (mat == 0 && threadIdx.x < 11) {
      int j = threadIdx.x;
      sums_out[j] = (float)S[j];
      sums_out[11 + j] = (j >= 1) ? (float)((double)j / 10.0 * S[j - 1]) : 0.f;
    }
    return;
  }
  int idx = (blockIdx.x - 4) * 256 + threadIdx.x;
  if (idx < 221184) {           // Waug[col][k], k in [0,288)
    int col = idx / 288, k = idx - col * 288;
    float v;
    if (k < 256)       v = Whh[k * 768 + col];
    else if (k < 261)  v = Wih[(k - 256) * 768 + col];
    else if (k == 261) v = gb[col];
    else               v = 0.f;
    Waug[idx] = f2bf(v);
  } else if (idx < 352256) {    // W1T[col][k]
    int j = idx - 221184;
    int col = j >> 8, k = j & 255;
    W1T[j] = f2bf(W1[k * 512 + col]);
  } else if (idx < 942080) {    // HaugA full init
    int j = idx - 352256;
    int row = j / 288, k = j - row * 288;
    float v;
    if (k < 256)       v = h0[k];
    else if (k == 256) v = obs[row * 20 + 0];
    else if (k == 257) v = obs[row * 20 + 10];
    else if (k == 258) v = dimx[row * 10 + 0];
    else if (k == 259) v = dimy[row * 10 + 0];
    else if (k == 260) v = psi[row * 10 + 0];
    else if (k == 261) v = 1.0f;
    else               v = 0.f;
    HaugA[row * 288 + k] = f2bf(v);
  } else if (idx < 995328) {    // HaugB: constant tail zeros (k=262..287)
    int j = idx - 942080;
    int row = j / 26, k = 262 + (j - row * 26);
    HaugB[row * 288 + k] = 0;
  } else if (idx < 1011712) {   // W2T[col][k] (32x512, cols>=22 zero)
    int j = idx - 995328;
    int col = j >> 9, k = j & 511;
    W2T[j] = f2bf(col < 22 ? W2[k * 22 + col] : 0.f);
  }
}

// ---------------- GRU step: 512 blocks, direct-from-L2 fragments, no LDS ----------------
#define MFMA __builtin_amdgcn_mfma_f32_16x16x32_bf16
__global__ __launch_bounds__(256) void gru_step(
    const unsigned short* __restrict__ Waug,
    const unsigned short* __restrict__ HaugC, unsigned short* __restrict__ HaugN,
    float* __restrict__ Hf32, const float* __restrict__ h0,
    const float* __restrict__ obs, const float* __restrict__ dimx,
    const float* __restrict__ dimy, const float* __restrict__ psi,
    int s)
{
  const int tid = threadIdx.x;
  const int m0 = blockIdx.x * 32;
  const int c0 = blockIdx.y * 32;
  const int lane = tid & 63, w = tid >> 6;
  const int l15 = lane & 15, g4 = lane >> 4;
  const int mi = w >> 1, cg = w & 1;

  const unsigned short* Arow = HaugC + (size_t)(m0 + mi * 16 + l15) * 288 + g4 * 8;
  const unsigned short* Bcol = Waug + (size_t)(c0 + cg * 16 + l15) * 288 + g4 * 8;

  f32x4 accz = {0.f,0.f,0.f,0.f}, accr = {0.f,0.f,0.f,0.f};
  f32x4 anh = {0.f,0.f,0.f,0.f}, anx = {0.f,0.f,0.f,0.f};

  #pragma unroll
  for (int kc = 0; kc < 9; ++kc) {
    bf16x8 a  = *(const bf16x8*)(Arow + kc * 32);
    bf16x8 bz = *(const bf16x8*)(Bcol + kc * 32);
    bf16x8 br = *(const bf16x8*)(Bcol + 256 * 288 + kc * 32);
    bf16x8 bn = *(const bf16x8*)(Bcol + 512 * 288 + kc * 32);
    accz = MFMA(a, bz, accz, 0, 0, 0);
    accr = MFMA(a, br, accr, 0, 0, 0);
    if (kc < 8) anh = MFMA(a, bn, anh, 0, 0, 0);
    else        anx = MFMA(a, bn, anx, 0, 0, 0);
  }

  const int colh = c0 + cg * 16 + l15;
  float h0c = (s == 0) ? h0[colh] : 0.f;
  #pragma unroll
  for (int rg = 0; rg < 4; ++rg) {
    int row = m0 + mi * 16 + g4 * 4 + rg;
    float hold = (s == 0) ? h0c : Hf32[(size_t)row * 256 + colh];
    float z = 1.f / (1.f + __expf(-accz[rg]));
    float rr = 1.f / (1.f + __expf(-accr[rg]));
    float nn = tanhf(anx[rg] + rr * anh[rg]);
    float hnew = (1.f - z) * nn + z * hold;
    Hf32[(size_t)row * 256 + colh] = hnew;
    HaugN[(size_t)row * 288 + colh] = f2bf(hnew);
  }
  if (blockIdx.y == 0 && s < 9 && tid < 192) {
    int row = m0 + tid / 6, e = tid - (tid / 6) * 6;
    int s1 = s + 1;
    float v = (e == 0) ? obs[row * 20 + s1] : (e == 1) ? obs[row * 20 + 10 + s1]
            : (e == 2) ? dimx[row * 10 + s1] : (e == 3) ? dimy[row * 10 + s1]
            : (e == 4) ? psi[row * 10 + s1] : 1.0f;
    HaugN[(size_t)row * 288 + 256 + e] = f2bf(v);
  }
}

// ---------------- fused MLP: 128 blocks x 16 rows; acts stay in LDS ----------------
__global__ __launch_bounds__(256) void mlp_fused(
    const unsigned short* __restrict__ Haug, const unsigned short* __restrict__ W1T,
    const float* __restrict__ b1, const unsigned short* __restrict__ W2T,
    const float* __restrict__ b2, float* __restrict__ lam)
{
  __shared__ __align__(16) unsigned short As[4096];    // 8 tiles x 512 (16 rows x K=256)
  __shared__ __align__(16) unsigned short Acts[8192];  // 16 tiles x 512 (16 rows x K=512)
  const int tid = threadIdx.x;
  const int m0 = blockIdx.x * 16;
  const int lane = tid & 63, w = tid >> 6, l15 = lane & 15, g4 = lane >> 4;

  #pragma unroll
  for (int r = 0; r < 2; ++r) {
    int j = tid + 256 * r;
    int tile = j >> 6, q = j & 63, ci = q >> 2, ks = q & 3;
    const unsigned short* src = Haug + (size_t)(m0 + ci) * 288 + tile * 32 + ks * 8;
    *(int4*)&As[tile * 512 + q * 8] = *(const int4*)src;
  }
  __syncthreads();
  const int foff = (l15 * 4 + g4) * 8;

  // MLP1: wave w covers cols w*128..+128
  f32x4 acc[8];
  #pragma unroll
  for (int nt = 0; nt < 8; ++nt) acc[nt] = (f32x4){0.f,0.f,0.f,0.f};
  #pragma unroll
  for (int kc = 0; kc < 8; ++kc) {
    bf16x8 a = *(const bf16x8*)&As[kc * 512 + foff];
    int kk = kc * 32 + g4 * 8;
    #pragma unroll
    for (int nt = 0; nt < 8; ++nt) {
      int col = w * 128 + nt * 16 + l15;
      bf16x8 b = *(const bf16x8*)&W1T[(size_t)col * 256 + kk];
      acc[nt] = MFMA(a, b, acc[nt], 0, 0, 0);
    }
  }
  #pragma unroll
  for (int nt = 0; nt < 8; ++nt) {
    int col = w * 128 + nt * 16 + l15;
    float bb = b1[col];
    int tile = col >> 5, sub = (col >> 3) & 3, e = col & 7;
    #pragma unroll
    for (int rg = 0; rg < 4; ++rg) {
      int row = g4 * 4 + rg;
      float v = fmaxf(acc[nt][rg] + bb, 0.f);
      Acts[tile * 512 + (row * 4 + sub) * 8 + e] = f2bf(v);
    }
  }
  __syncthreads();

  // MLP2: waves 0,1 cover cols 0..31 (22 used), K=512
  if (w < 2) {
    int col = w * 16 + l15;
    f32x4 a2 = {0.f,0.f,0.f,0.f};
    #pragma unroll
    for (int kc = 0; kc < 16; ++kc) {
      bf16x8 a = *(const bf16x8*)&Acts[kc * 512 + foff];
      bf16x8 b = *(const bf16x8*)&W2T[(size_t)col * 512 + kc * 32 + g4 * 8];
      a2 = MFMA(a, b, a2, 0, 0, 0);
    }
    if (col < 22) {
      float bb = b2[col];
      #pragma unroll
      for (int rg = 0; rg < 4; ++rg)
        lam[(size_t)(m0 + g4 * 4 + rg) * 22 + col] = a2[rg] + bb;
    }
  }
}

// ---------------- ADMM solver: 2 problems per 256-thread block, round-6 phases ----------------
__global__ __launch_bounds__(256) void solver(
    const float* __restrict__ ise, const float* __restrict__ goal,
    const float* __restrict__ obs, const float* __restrict__ psi,
    const float* __restrict__ dimx, const float* __restrict__ dimy,
    const float* __restrict__ yub, const float* __restrict__ ylb,
    const float* __restrict__ lam, const float* __restrict__ kkt,
    const float* __restrict__ Gxm, const float* __restrict__ Gym,
    const float* __restrict__ Mxm, const float* __restrict__ Mym,
    const float* __restrict__ sums, float* __restrict__ out)
{
  __shared__ __align__(16) float Pt[3][11][108];       // shared by both problems
  __shared__ __align__(16) float red[2][7][108];
  __shared__ float redout[2][7][11];
  __shared__ float cx[2][11], cy[2][11], lx[2][11], ly[2][11], cx0[2][11], cy0[2][11];
  __shared__ float kxB[2][11], kyB[2][11], hx[2][11], hy[2][11];
  __shared__ float rhsx[2][15], rhsy[2][14];
  __shared__ float xc[2][30], yc[2][30], sa_[2][10], sb_[2][10], sab[2][10], sab2[2][10];

  const int tid = threadIdx.x;
  const int pr = tid >> 7, lt = tid & 127;
  const int b = blockIdx.x * 2 + pr;

  if (tid < 100) {              // Pt: fill once (problem-independent)
    float t = tid * (1.0f / 99.0f);
    float tjm2 = 0.f, tjm1 = 0.f, tj = 1.f;
    #pragma unroll
    for (int j = 0; j < 11; ++j) {
      Pt[0][j][tid] = tj;
      Pt[1][j][tid] = 0.1f * (float)j * tjm1;
      Pt[2][j][tid] = 0.01f * (float)(j * (j - 1)) * tjm2;
      tjm2 = tjm1; tjm1 = tj; tj *= t;
    }
  }
  if (lt < 10) {
    int o = lt;
    float xo = obs[b * 20 + o], yo = obs[b * 20 + 10 + o];
    float dx = dimx[b * 10 + o], dy = dimy[b * 10 + o], ps = psi[b * 10 + o];
    float sp, cp;
    __sincosf(ps, &sp, &cp);
    float r1 = 0.5f * (dx - dy);
    xc[pr][o * 3] = xo; xc[pr][o * 3 + 1] = xo + r1 * cp; xc[pr][o * 3 + 2] = xo - r1 * cp;
    yc[pr][o * 3] = yo; yc[pr][o * 3 + 1] = yo + r1 * sp; yc[pr][o * 3 + 2] = yo - r1 * sp;
    float rad = 0.5f * dy;
    float av = 3.2f + rad, bv = 1.7f + rad;
    sa_[pr][o] = av; sb_[pr][o] = bv; sab[pr][o] = av * bv; sab2[pr][o] = av * bv * av * bv;
  }
  if (lt < 11) { lx[pr][lt] = lam[b * 22 + lt]; ly[pr][lt] = lam[b * 22 + 11 + lt]; }
  const float vx0 = ise[b * 6 + 2], vy0 = ise[b * 6 + 3];
  if (lt == 0) {
    float x0 = ise[b * 6 + 0], y0 = ise[b * 6 + 1];
    float ax0 = ise[b * 6 + 4], ay0 = ise[b * 6 + 5];
    rhsx[pr][11] = x0; rhsx[pr][12] = vx0; rhsx[pr][13] = ax0; rhsx[pr][14] = goal[b * 2 + 0];
    rhsy[pr][11] = y0; rhsy[pr][12] = vy0; rhsy[pr][13] = ay0;
  }
  {
    float vdes = sqrtf(vx0 * vx0 + vy0 * vy0);
    float gy = goal[b * 2 + 1];
    if (lt < 11) { rhsx[pr][lt] = 2.f * vdes * sums[11 + lt]; rhsy[pr][lt] = gy * sums[lt]; }
  }
  const float yU = yub[b], yL = ylb[b];
  __syncthreads();
  if (lt < 11) {
    const float* K = kkt + 2 * 176 + lt * 16;
    float s = 0.f;
    #pragma unroll
    for (int j = 0; j < 15; ++j) s += K[j] * rhsx[pr][j];
    cx0[pr][lt] = s; cx[pr][lt] = s;
    const float* Kx = kkt + lt * 16;
    float kb = 0.f;
    #pragma unroll
    for (int c = 0; c < 4; ++c) kb += Kx[11 + c] * rhsx[pr][11 + c];
    kxB[pr][lt] = kb;
  } else if (lt >= 16 && lt < 27) {
    int i = lt - 16;
    const float* K = kkt + 3 * 176 + i * 16;
    float s = 0.f;
    #pragma unroll
    for (int j = 0; j < 14; ++j) s += K[j] * rhsy[pr][j];
    cy0[pr][i] = s; cy[pr][i] = s;
    const float* Ky = kkt + 176 + i * 16;
    float kb = 0.f;
    #pragma unroll
    for (int c = 0; c < 3; ++c) kb += Ky[11 + c] * rhsy[pr][11 + c];
    kyB[pr][i] = kb;
  }
  __syncthreads();
  if (lt < 11) {
    float s = cx0[pr][lt];
    #pragma unroll
    for (int i = 0; i < 11; ++i) s += Mxm[lt * 16 + i] * kxB[pr][i];
    hx[pr][lt] = s;
  } else if (lt >= 16 && lt < 27) {
    int j = lt - 16;
    float s = cy0[pr][j];
    #pragma unroll
    for (int i = 0; i < 11; ++i) s += Mym[j * 16 + i] * kyB[pr][i];
    hy[pr][j] = s;
  }
  __syncthreads();

  for (int it = 0; it < 5; ++it) {
    // ---- phase 1: per-s-point nonlinear projections ----
    if (lt < 100) {
      float t = lt * (1.0f / 99.0f);
      float x = 0, y = 0, xd = 0, yd = 0, xdd = 0, ydd = 0;
      {
        float tjm2 = 0, tjm1 = 0, tj = 1;
        #pragma unroll
        for (int j = 0; j < 11; ++j) {
          float cj = cx[pr][j], dj = cy[pr][j];
          x += cj * tj; y += dj * tj;
          float pd = 0.1f * (float)j * tjm1;
          xd += cj * pd; yd += dj * pd;
          float pdd = 0.01f * (float)(j * (j - 1)) * tjm2;
          xdd += cj * pdd; ydd += dj * pdd;
          tjm2 = tjm1; tjm1 = tj; tj *= t;
        }
      }
      float Sbx = 0.f, Sby = 0.f;
      for (int oi = 0; oi < 10; ++oi) {
        float A = sa_[pr][oi], B = sb_[pr][oi], AB = sab[pr][oi], AB2 = sab2[pr][oi];
        #pragma unroll
        for (int cc = 0; cc < 3; ++cc) {
          int o = oi * 3 + cc;
          float xcc = xc[pr][o], ycc = yc[pr][o];
          float wc = x - xcc, wsv = y - ycc;
          float p = wsv * A, q = wc * B;
          float h2 = p * p + q * q;
          float rin = rsqrtf(h2 + 1e-20f);
          float sc = AB * rin;
          bool outside = h2 >= AB2;
          Sbx += outside ? x : fmaf(wc, sc, xcc);
          Sby += outside ? y : fmaf(wsv, sc, ycc);
        }
      }
      bool clipv = (xd <= 0.f) || (fabsf(yd) > xd * 0.43463135f);
      float cv, sv;
      if (clipv) { cv = 0.91712081f; sv = copysignf(0.39860934f, yd); }
      else { float ri = rsqrtf(fmaxf(xd * xd + yd * yd, 1e-24f)); cv = xd * ri; sv = yd * ri; }
      float dv = fminf(fmaxf(xd * cv + yd * sv, 0.001f), 18.f);
      float qa = xdd + 1e-4f, pa = ydd + 1e-4f;
      float ria = rsqrtf(pa * pa + qa * qa + 1e-30f);
      float caa = qa * ria, saa = pa * ria;
      float da = fminf(fmaxf(xdd * caa + ydd * saa, 0.f), 6.f);
      red[pr][0][lt] = Sbx; red[pr][1][lt] = Sby;
      red[pr][2][lt] = dv * cv; red[pr][3][lt] = dv * sv;
      red[pr][4][lt] = da * caa; red[pr][5][lt] = da * saa;
      red[pr][6][lt] = fminf(y, yU) - fminf(-y, -yL);
    }
    __syncthreads();
    // ---- phase 2: 7x(100->11) reduction ----
    if (lt < 77) {
      int a = lt / 11, j = lt - a * 11;
      int wt = (a < 2) ? 0 : (a < 4) ? 1 : (a < 6) ? 2 : 0;
      const float4* rp = (const float4*)(&red[pr][a][0]);
      const float4* wp = (const float4*)(&Pt[wt][j][0]);
      float s = 0.f;
      #pragma unroll
      for (int k = 0; k < 25; ++k) {
        float4 rv = rp[k], wv = wp[k];
        s += rv.x * wv.x + rv.y * wv.y + rv.z * wv.z + rv.w * wv.w;
      }
      redout[pr][a][j] = s;
    }
    __syncthreads();
    // ---- phase 3: top build (22 parallel threads) ----
    if (lt < 11)
      rhsx[pr][lt] = lx[pr][lt] + cx0[pr][lt] + redout[pr][0][lt] + redout[pr][2][lt] + redout[pr][4][lt];
    else if (lt >= 16 && lt < 27) {
      int j = lt - 16;
      rhsy[pr][j] = ly[pr][j] + cy0[pr][j] + redout[pr][1][j] + redout[pr][3][j] + redout[pr][5][j] + redout[pr][6][j];
    }
    __syncthreads();
    // ---- phase 4: c update + lambda update via precomputed G/K ----
    if (lt < 11) {
      const float* K = kkt + lt * 16;
      const float* G = Gxm + lt * 16;
      float sc = kxB[pr][lt], sl = -hx[pr][lt];
      #pragma unroll
      for (int i = 0; i < 11; ++i) {
        float r = rhsx[pr][i];
        sc += K[i] * r;
        sl += G[i] * r;
      }
      cx[pr][lt] = sc; lx[pr][lt] = sl;
    } else if (lt >= 16 && lt < 27) {
      int j = lt - 16;
      const float* K = kkt + 176 + j * 16;
      const float* G = Gym + j * 16;
      float sc = kyB[pr][j], sl = -hy[pr][j];
      #pragma unroll
      for (int i = 0; i < 11; ++i) {
        float r = rhsy[pr][i];
        sc += K[i] * r;
        sl += G[i] * r;
      }
      cy[pr][j] = sc; ly[pr][j] = sl;
    }
    __syncthreads();
  }
  if (lt < 11) out[b * 22 + lt] = cx[pr][lt];
  else if (lt >= 16 && lt < 27) out[b * 22 + 11 + (lt - 16)] = cy[pr][lt - 16];
}

extern "C" void kernel_launch(void* const* d_in, const int* in_sizes, int n_in,
                              void* d_out, int out_size, void* d_ws, size_t ws_size,
                              hipStream_t stream) {
  const float* ise  = (const float*)d_in[0];
  const float* goal = (const float*)d_in[1];
  const float* obs  = (const float*)d_in[2];
  const float* psi  = (const float*)d_in[3];
  const float* dimx = (const float*)d_in[4];
  const float* dimy = (const float*)d_in[5];
  const float* yub  = (const float*)d_in[6];
  const float* ylb  = (const float*)d_in[7];
  const float* Wih  = (const float*)d_in[8];
  const float* Whh  = (const float*)d_in[9];
  const float* gb   = (const float*)d_in[10];
  const float* h0   = (const float*)d_in[11];
  const float* W1   = (const float*)d_in[12];
  const float* b1   = (const float*)d_in[13];
  const float* W2   = (const float*)d_in[14];
  const float* b2   = (const float*)d_in[15];

  char* ws = (char*)d_ws;
  unsigned short* Waug  = (unsigned short*)(ws + WS_WAUG);
  unsigned short* W1T   = (unsigned short*)(ws + WS_W1T);
  unsigned short* W2T   = (unsigned short*)(ws + WS_W2T);
  unsigned short* HaugA = (unsigned short*)(ws + WS_HAUGA);
  unsigned short* HaugB = (unsigned short*)(ws + WS_HAUGB);
  float* Hf32 = (float*)(ws + WS_HF32);
  float* lamb = (float*)(ws + WS_LAM);
  float* kkt  = (float*)(ws + WS_KKT);
  float* Gxm  = (float*)(ws + WS_GX);
  float* Gym  = (float*)(ws + WS_GY);
  float* Mxm  = (float*)(ws + WS_MX);
  float* Mym  = (float*)(ws + WS_MY);
  float* sums = (float*)(ws + WS_SUMS);

  prep<<<3956, 256, 0, stream>>>(Whh, Wih, gb, W1, W2, h0, obs, dimx, dimy, psi,
                                 Waug, W1T, W2T, HaugA, HaugB,
                                 kkt, Gxm, Gym, Mxm, Mym, sums);
  for (int s = 0; s < 10; ++s) {
    const unsigned short* hc = (s & 1) ? HaugB : HaugA;
    unsigned short* hn = (s & 1) ? HaugA : HaugB;
    gru_step<<<dim3(64, 8), 256, 0, stream>>>(Waug, hc, hn, Hf32, h0,
                                              obs, dimx, dimy, psi, s);
  }
  mlp_fused<<<128, 256, 0, stream>>>(HaugA, W1T, b1, W2T, b2, lamb);
  solver<<<1024, 256, 0, stream>>>(ise, goal, obs, psi, dimx, dimy, yub, ylb,
                                   lamb, kkt, Gxm, Gym, Mxm, Mym, sums, (float*)d_out);
  (void)in_sizes; (void)n_in; (void)out_size; (void)ws_size;
}